// Round 10
// baseline (346.387 us; speedup 1.0000x reference)
//
#include <hip/hip_runtime.h>
#include <hip/hip_cooperative_groups.h>
#include <stdint.h>

namespace cg = cooperative_groups;

typedef __attribute__((ext_vector_type(4))) float float4v;

#define D 4096
#define R 16
#define NW 192     // adapters
#define LB 1280    // lora rows
#define NBL 256
#define MAXB 32    // max bucket size (actual max ~16-17, binomial(1280,1/192))
#define GRID (NW * 4)   // 768 blocks = 3/CU x 256 CU exactly (coop co-residency)

// ---- round-10: single cooperative kernel, 3 phases, 2 grid syncs ----------
// r9 post-mortem: rocprof exposed the "fixed" ~100us as TWO 256MiB workspace
// re-poison fills at 6.6 TB/s (82% peak) -- harness-side, untouchable. But it
// also proves the chip streams 4x faster than our kernels (1.5 TB/s) in this
// region, and our 3-dispatch chain pays 2 full kernel-boundary drains.
// This round: fuse h-pass / y-pass / sum4 into ONE cooperative kernel:
//  - 768 blocks x 256 thr = exactly 3 blocks/CU: co-residency guaranteed,
//    grid.sync() (~1-2us) replaces kernel-boundary drains.
//  - breg[16] (B tile, 64 VGPR) issued BEFORE phase A: B's 50MB streams
//    under phase-A compute. Safe now: at 256 thr + __launch_bounds__(256,3)
//    the VGPR cap is ~170 (vs the fatal 64-target at 1024 thr that spilled
//    r3/r6). Spill check: WRITE_SIZE ~21MB, VGPR 140-168.
//  - empty-bucket blocks skip phase bodies but still reach both grid syncs.
//  - hp[4][1280][16] lives in ws after ybuf (fill-poison-safe: every row is
//    in exactly one bucket, so phase A writes every hp entry phase B reads).
// Fallback: if hipLaunchCooperativeKernel errors (e.g. capture refusal),
// launch the r9-proven 3-kernel chain -- worst case = current perf.
__global__ __launch_bounds__(256, 3) void fused_coop(
    const float* __restrict__ x,
    const float* __restrict__ A,
    const float* __restrict__ B,
    const int* __restrict__ xids,
    const int* __restrict__ wids,
    float* __restrict__ ybuf,   // ws[0)      : [NBL*4][D]
    float* __restrict__ hp,     // ws[16MB)   : [4][LB][R]
    float* __restrict__ out)    // [512][D]
{
    const int bid = blockIdx.x;
    const int w = bid >> 2;            // adapter
    const int c = bid & 3;             // d-chunk (1024 cols)
    const int t = threadIdx.x;
    const int lane = t & 63;
    const int wv = t >> 6;             // 4 waves

    __shared__ int list[MAXB];
    __shared__ int xidl[MAXB];
    __shared__ int cnt;
    __shared__ float hws[MAXB][4][17];   // +1 pad kills bank conflicts
    __shared__ float xs[4][256];         // per-wave x slice
    __shared__ float hl[MAXB][R];

    // ---- bucket scan (shared by phases A and B) ----
    if (t == 0) cnt = 0;
    __syncthreads();
    for (int i = t; i < LB; i += 256)
        if (wids[i] == w) { int q = atomicAdd(&cnt, 1); if (q < MAXB) list[q] = i; }
    __syncthreads();
    const int n = cnt > MAXB ? MAXB : cnt;
    if (t < n) xidl[t] = xids[list[t]];
    __syncthreads();

    const int col = 1024 * c + 4 * t;    // this block's d-columns (phases B/C)

    // ---- B tile issued FIRST: independent of phase A, streams under it ----
    const float* Bw = B + (size_t)w * R * D + col;
    float4v breg[R];
    #pragma unroll
    for (int r = 0; r < R; ++r) breg[r] = *(const float4v*)(Bw + (size_t)r * D);

    // ---- phase A: hp[c][row][r] = x[row, chunk c] . A[chunk c] ----
    if (n > 0) {
        const int xoff = 1024 * c + 256 * wv + 4 * lane;   // coalesced 1KB/wave
        float4v xv = *(const float4v*)(x + (size_t)xidl[0] * D + xoff);

        const float4v* af = (const float4v*)(A + ((size_t)w * D + 1024 * c) * R);
        float4v a[16];
        #pragma unroll
        for (int k = 0; k < 16; ++k) a[k] = af[1024 * wv + 64 * k + lane];

        // pipelined rows; xs is wave-private (in-order DS) -> no syncs
        *(float4v*)(&xs[wv][4 * lane]) = xv;
        for (int i = 0; i < n; ++i) {
            float4v xvn;
            if (i + 1 < n)
                xvn = *(const float4v*)(x + (size_t)xidl[i + 1] * D + xoff);
            float h0 = 0.f, h1 = 0.f, h2 = 0.f, h3 = 0.f;
            #pragma unroll
            for (int k = 0; k < 16; ++k) {
                const float xd = xs[wv][(lane >> 2) + 16 * k];   // 4-lane bcast
                h0 += xd * a[k][0]; h1 += xd * a[k][1];
                h2 += xd * a[k][2]; h3 += xd * a[k][3];
            }
            #pragma unroll
            for (int off = 4; off <= 32; off <<= 1) {
                h0 += __shfl_xor(h0, off, 64); h1 += __shfl_xor(h1, off, 64);
                h2 += __shfl_xor(h2, off, 64); h3 += __shfl_xor(h3, off, 64);
            }
            if (lane < 4) {                  // lane L holds r = 4L..4L+3
                hws[i][wv][4 * lane + 0] = h0;
                hws[i][wv][4 * lane + 1] = h1;
                hws[i][wv][4 * lane + 2] = h2;
                hws[i][wv][4 * lane + 3] = h3;
            }
            if (i + 1 < n)
                *(float4v*)(&xs[wv][4 * lane]) = xvn;
        }
        __syncthreads();
        for (int idx = t; idx < n * R; idx += 256) {
            const int i = idx >> 4, r = idx & 15;
            hp[((size_t)c * LB + list[i]) * R + r] =
                hws[i][0][r] + hws[i][1][r] + hws[i][2][r] + hws[i][3][r];
        }
    }

    cg::this_grid().sync();

    // ---- phase B: y[row, chunk c] = 2 * h[row] . B[chunk c] ----
    if (n > 0) {
        for (int idx = t; idx < n * R; idx += 256) {
            const int i = idx >> 4, r = idx & 15;
            const size_t base = (size_t)list[i] * R + r;
            hl[i][r] = hp[base] + hp[(size_t)LB * R + base]
                     + hp[2 * (size_t)LB * R + base] + hp[3 * (size_t)LB * R + base];
        }
        __syncthreads();
        for (int i = 0; i < n; ++i) {
            const int b = list[i];
            float4v acc = {0.f, 0.f, 0.f, 0.f};
            #pragma unroll
            for (int r = 0; r < R; ++r) {
                const float hr = hl[i][r];          // LDS broadcast
                acc[0] += hr * breg[r][0];
                acc[1] += hr * breg[r][1];
                acc[2] += hr * breg[r][2];
                acc[3] += hr * breg[r][3];
            }
            #pragma unroll
            for (int k = 0; k < 4; ++k) acc[k] *= 2.0f;
            if (b < NBL * 4) {
                *(float4v*)(ybuf + (size_t)b * D + col) = acc;       // unique writer
            } else {
                *(float4v*)(out + (size_t)(NBL + (b - NBL * 4)) * D + col) = acc;
            }
        }
    }

    cg::this_grid().sync();

    // ---- phase C: out[o] = sum of ybuf[4o..4o+3] (1024 tasks / 768 blocks) --
    for (int task = bid; task < NBL * 4; task += GRID) {
        const int o = task >> 2, q = task & 3;
        const int col2 = q * 1024 + 4 * t;
        const float* y0 = ybuf + (size_t)(4 * o) * D + col2;
        float4v v0 = *(const float4v*)(y0);
        float4v v1 = *(const float4v*)(y0 + D);
        float4v v2 = *(const float4v*)(y0 + 2 * D);
        float4v v3 = *(const float4v*)(y0 + 3 * D);
        float4v s;
        #pragma unroll
        for (int k = 0; k < 4; ++k) s[k] = (v0[k] + v1[k]) + (v2[k] + v3[k]);
        *(float4v*)(out + (size_t)o * D + col2) = s;
    }
}

// ================= fallback: r9-proven 3-kernel chain ======================
__global__ __launch_bounds__(256) void h_kernel(
    const float* __restrict__ x,
    const float* __restrict__ A,
    const int* __restrict__ xids,
    const int* __restrict__ wids,
    float* __restrict__ hp)
{
    const int w = blockIdx.x >> 2;
    const int c = blockIdx.x & 3;
    const int t = threadIdx.x;
    const int lane = t & 63;
    const int wv = t >> 6;

    __shared__ int list[MAXB];
    __shared__ int xidl[MAXB];
    __shared__ int cnt;
    __shared__ float hws[MAXB][4][17];
    __shared__ float xs[4][256];

    if (t == 0) cnt = 0;
    __syncthreads();
    for (int i = t; i < LB; i += 256)
        if (wids[i] == w) { int q = atomicAdd(&cnt, 1); if (q < MAXB) list[q] = i; }
    __syncthreads();
    const int n = cnt > MAXB ? MAXB : cnt;
    if (n == 0) return;
    if (t < n) xidl[t] = xids[list[t]];
    __syncthreads();

    const int xoff = 1024 * c + 256 * wv + 4 * lane;
    float4v xv = *(const float4v*)(x + (size_t)xidl[0] * D + xoff);

    const float4v* af = (const float4v*)(A + ((size_t)w * D + 1024 * c) * R);
    float4v a[16];
    #pragma unroll
    for (int k = 0; k < 16; ++k) a[k] = af[1024 * wv + 64 * k + lane];

    *(float4v*)(&xs[wv][4 * lane]) = xv;
    for (int i = 0; i < n; ++i) {
        float4v xvn;
        if (i + 1 < n)
            xvn = *(const float4v*)(x + (size_t)xidl[i + 1] * D + xoff);
        float h0 = 0.f, h1 = 0.f, h2 = 0.f, h3 = 0.f;
        #pragma unroll
        for (int k = 0; k < 16; ++k) {
            const float xd = xs[wv][(lane >> 2) + 16 * k];
            h0 += xd * a[k][0]; h1 += xd * a[k][1];
            h2 += xd * a[k][2]; h3 += xd * a[k][3];
        }
        #pragma unroll
        for (int off = 4; off <= 32; off <<= 1) {
            h0 += __shfl_xor(h0, off, 64); h1 += __shfl_xor(h1, off, 64);
            h2 += __shfl_xor(h2, off, 64); h3 += __shfl_xor(h3, off, 64);
        }
        if (lane < 4) {
            hws[i][wv][4 * lane + 0] = h0;
            hws[i][wv][4 * lane + 1] = h1;
            hws[i][wv][4 * lane + 2] = h2;
            hws[i][wv][4 * lane + 3] = h3;
        }
        if (i + 1 < n)
            *(float4v*)(&xs[wv][4 * lane]) = xvn;
    }
    __syncthreads();
    for (int idx = t; idx < n * R; idx += 256) {
        const int i = idx >> 4, r = idx & 15;
        hp[((size_t)c * LB + list[i]) * R + r] =
            hws[i][0][r] + hws[i][1][r] + hws[i][2][r] + hws[i][3][r];
    }
}

__global__ __launch_bounds__(256) void y_kernel(
    const float* __restrict__ B,
    const int* __restrict__ wids,
    float* __restrict__ ybuf,
    const float* __restrict__ hp,
    float* __restrict__ out)
{
    const int w = blockIdx.x >> 2;
    const int cq = blockIdx.x & 3;
    const int t = threadIdx.x;

    __shared__ int list[MAXB];
    __shared__ int cnt;
    __shared__ float hl[MAXB][R];

    if (t == 0) cnt = 0;
    __syncthreads();
    for (int i = t; i < LB; i += 256)
        if (wids[i] == w) { int q = atomicAdd(&cnt, 1); if (q < MAXB) list[q] = i; }
    __syncthreads();
    const int n = cnt > MAXB ? MAXB : cnt;
    if (n == 0) return;
    __syncthreads();

    const int col = 1024 * cq + 4 * t;
    const float* Bw = B + (size_t)w * R * D + col;
    float4v breg[R];
    #pragma unroll
    for (int r = 0; r < R; ++r) breg[r] = *(const float4v*)(Bw + (size_t)r * D);

    for (int idx = t; idx < n * R; idx += 256) {
        const int i = idx >> 4, r = idx & 15;
        const size_t base = (size_t)list[i] * R + r;
        hl[i][r] = hp[base] + hp[(size_t)LB * R + base]
                 + hp[2 * (size_t)LB * R + base] + hp[3 * (size_t)LB * R + base];
    }
    __syncthreads();

    for (int i = 0; i < n; ++i) {
        const int b = list[i];
        float4v acc = {0.f, 0.f, 0.f, 0.f};
        #pragma unroll
        for (int r = 0; r < R; ++r) {
            const float hr = hl[i][r];
            acc[0] += hr * breg[r][0];
            acc[1] += hr * breg[r][1];
            acc[2] += hr * breg[r][2];
            acc[3] += hr * breg[r][3];
        }
        #pragma unroll
        for (int k = 0; k < 4; ++k) acc[k] *= 2.0f;
        if (b < NBL * 4) {
            *(float4v*)(ybuf + (size_t)b * D + col) = acc;
        } else {
            *(float4v*)(out + (size_t)(NBL + (b - NBL * 4)) * D + col) = acc;
        }
    }
}

__global__ __launch_bounds__(256) void sum4_kernel(
    const float* __restrict__ ybuf,
    float* __restrict__ out)
{
    const int o = blockIdx.x >> 2;
    const int q = blockIdx.x & 3;
    const int col = q * 1024 + 4 * threadIdx.x;
    const float* y0 = ybuf + (size_t)(4 * o) * D + col;
    float4v v0 = *(const float4v*)(y0);
    float4v v1 = *(const float4v*)(y0 + D);
    float4v v2 = *(const float4v*)(y0 + 2 * D);
    float4v v3 = *(const float4v*)(y0 + 3 * D);
    float4v s;
    #pragma unroll
    for (int k = 0; k < 4; ++k) s[k] = (v0[k] + v1[k]) + (v2[k] + v3[k]);
    *(float4v*)(out + (size_t)o * D + col) = s;
}

extern "C" void kernel_launch(void* const* d_in, const int* in_sizes, int n_in,
                              void* d_out, int out_size, void* d_ws, size_t ws_size,
                              hipStream_t stream) {
    const float* x    = (const float*)d_in[0];
    const float* A    = (const float*)d_in[1];
    const float* B    = (const float*)d_in[2];
    const int*   xids = (const int*)d_in[3];
    const int*   wids = (const int*)d_in[4];
    float*       out  = (float*)d_out;

    float* ybuf = (float*)d_ws;                              // 16 MB
    float* hp   = (float*)d_ws + (size_t)(NBL * 4) * D;      // +320 KB

    void* args[] = {(void*)&x, (void*)&A, (void*)&B, (void*)&xids,
                    (void*)&wids, (void*)&ybuf, (void*)&hp, (void*)&out};
    hipError_t err = hipLaunchCooperativeKernel(
        (const void*)fused_coop, dim3(GRID), dim3(256), args, 0, stream);
    if (err != hipSuccess) {
        // fallback: r9-proven stream-ordered 3-kernel chain
        hipLaunchKernelGGL(h_kernel, dim3(GRID), dim3(256), 0, stream,
                           x, A, xids, wids, hp);
        hipLaunchKernelGGL(y_kernel, dim3(GRID), dim3(256), 0, stream,
                           B, wids, ybuf, hp, out);
        hipLaunchKernelGGL(sum4_kernel, dim3(NBL * 4), dim3(256), 0, stream,
                           ybuf, out);
    }
}

// Round 11
// 150.965 us; speedup vs baseline: 2.2945x; 2.2945x over previous
//
#include <hip/hip_runtime.h>
#include <stdint.h>

typedef __attribute__((ext_vector_type(4))) float float4v;

#define D 4096
#define R 16
#define NW 192     // adapters
#define LB 1280    // lora rows
#define NBL 256
#define MAXB 32    // max bucket size (actual max ~16-17, binomial(1280,1/192))
#define NWAVE 16   // waves per block

// ---------------- fused: per-adapter A->h->B->y ----------------
// ROUND-11 = exact revert to the round-4 proven best (149.4us end-to-end).
// r10 post-mortem: cooperative grid.sync costs ~90us/sync on 768 blocks
// (cross-XCD spin) -> 234us kernel. Reverted.
// Session ledger: end-to-end = ~80us harness re-poison fills (measured at
// 6.6TB/s, 82-85% of HBM peak -- the roofline, harness-side) + ~20us
// dispatch boundaries + ~48us kernel work. The 48us was invariant across
// six structures (fat 2-phase / parity-split / ILP pipeline / zero-VGPR
// B-DMA / fine 3-kernel / coop); atomics and register-held B both regressed.
// This file is the best measured configuration:
//  - coalesced LDS-staged x (1 dwordx4/lane/row), 2-deep row pipeline
//  - A tile in registers; B loads hoisted over the hws barrier (spill-free
//    slot: a[] dead there), VGPR=56
//  - ybuf+sum4 segment reduction (atomics proved 3x write traffic)
__global__ __launch_bounds__(1024, 4) void fused_kernel(
    const float* __restrict__ x,
    const float* __restrict__ A,
    const float* __restrict__ B,
    const int* __restrict__ xids,
    const int* __restrict__ wids,
    float* __restrict__ ybuf,   // [NBL*4][D]
    float* __restrict__ out)    // [512][D]
{
    const int w = blockIdx.x;
    const int t = threadIdx.x;
    const int lane = t & 63;
    const int wave = t >> 6;

    __shared__ int list[MAXB];
    __shared__ int xidl[MAXB];
    __shared__ int cnt;
    __shared__ float hws[MAXB][NWAVE][17];  // +1 pad: stride 17 kills bank conflicts
    __shared__ float hl[MAXB][R];
    __shared__ float xs[2][NWAVE][256];     // double-buffered per-wave x slices

    if (t == 0) cnt = 0;
    __syncthreads();
    for (int i = t; i < LB; i += 1024)
        if (wids[i] == w) { int q = atomicAdd(&cnt, 1); if (q < MAXB) list[q] = i; }
    __syncthreads();
    int n = cnt > MAXB ? MAXB : cnt;
    if (n == 0) return;
    if (t < n) xidl[t] = xids[list[t]];
    __syncthreads();

    // lane owns d = 256*wave + (lane>>2) + 16k (k=0..15), r = 4*(lane&3)+c.
    const int xcol = 256 * wave + 4 * lane;   // coalesced slice col for staging

    // issue row-0 x load first so it's in flight under the A burst
    float4v xv0 = *(const float4v*)(x + (size_t)xidl[0] * D + xcol);

    const float4v* af = (const float4v*)(A + (size_t)w * D * R);
    float4v a[16];
    #pragma unroll
    for (int k = 0; k < 16; ++k) a[k] = af[1024 * wave + 64 * k + lane];

#define ROW_COMPUTE(i, buf)                                               \
    { float h0 = 0.f, h1 = 0.f, h2 = 0.f, h3 = 0.f;                       \
      _Pragma("unroll")                                                   \
      for (int k = 0; k < 16; ++k) {                                      \
          const float xd = xs[buf][wave][(lane >> 2) + 16 * k];           \
          h0 += xd * a[k][0]; h1 += xd * a[k][1];                         \
          h2 += xd * a[k][2]; h3 += xd * a[k][3];                         \
      }                                                                   \
      _Pragma("unroll")                                                   \
      for (int off = 4; off <= 32; off <<= 1) {                           \
          h0 += __shfl_xor(h0, off, 64); h1 += __shfl_xor(h1, off, 64);   \
          h2 += __shfl_xor(h2, off, 64); h3 += __shfl_xor(h3, off, 64);   \
      }                                                                   \
      if (lane < 4) {                                                     \
          hws[i][wave][4 * lane + 0] = h0;                                \
          hws[i][wave][4 * lane + 1] = h1;                                \
          hws[i][wave][4 * lane + 2] = h2;                                \
          hws[i][wave][4 * lane + 3] = h3;                                \
      } }

    // ---- phase 1: h[i][r] = x[xid_i] . A, 2-deep pipelined, LDS-staged ----
    float4v xv1;
    *(float4v*)(&xs[0][wave][4 * lane]) = xv0;
    for (int i = 0; i < n; i += 2) {
        if (i + 1 < n)
            xv1 = *(const float4v*)(x + (size_t)xidl[i + 1] * D + xcol);
        ROW_COMPUTE(i, 0);
        if (i + 1 < n) {
            *(float4v*)(&xs[1][wave][4 * lane]) = xv1;
            if (i + 2 < n)
                xv0 = *(const float4v*)(x + (size_t)xidl[i + 2] * D + xcol);
            ROW_COMPUTE(i + 1, 1);
            if (i + 2 < n)
                *(float4v*)(&xs[0][wave][4 * lane]) = xv0;
        }
    }
#undef ROW_COMPUTE

    // B loads issued before the barrier: fetch overlaps hl-combine; a[] is
    // dead here so the allocator reuses its registers.
    const float* Bw = B + (size_t)w * R * D + 4 * t;
    float4v breg[R];
    #pragma unroll
    for (int r = 0; r < R; ++r) breg[r] = *(const float4v*)(Bw + (size_t)r * D);

    __syncthreads();
    for (int idx = t; idx < n * R; idx += 1024) {
        const int i = idx >> 4, r = idx & 15;
        float sacc = 0.f;
        #pragma unroll
        for (int j = 0; j < NWAVE; ++j) sacc += hws[i][j][r];
        hl[i][r] = sacc;
    }
    __syncthreads();

    // ---- phase 2: y = 2*h.B ----
    for (int i = 0; i < n; ++i) {
        const int b = list[i];
        float4v acc = {0.f, 0.f, 0.f, 0.f};
        #pragma unroll
        for (int r = 0; r < R; ++r) {
            const float hr = hl[i][r];         // LDS broadcast
            acc[0] += hr * breg[r][0];
            acc[1] += hr * breg[r][1];
            acc[2] += hr * breg[r][2];
            acc[3] += hr * breg[r][3];
        }
        #pragma unroll
        for (int k = 0; k < 4; ++k) acc[k] *= 2.0f;

        if (b < NBL * 4) {
            *(float4v*)(ybuf + (size_t)b * D + 4 * t) = acc;        // unique writer
        } else {
            *(float4v*)(out + (size_t)(NBL + (b - NBL * 4)) * D + 4 * t) = acc;
        }
    }
}

// ---------------- sum4: out[o] = ybuf[4o]+ybuf[4o+1]+ybuf[4o+2]+ybuf[4o+3] ---
__global__ __launch_bounds__(256) void sum4_kernel(
    const float* __restrict__ ybuf,
    float* __restrict__ out)
{
    const int o = blockIdx.x >> 2;            // 0..255
    const int q = blockIdx.x & 3;             // d-quarter
    const int col = q * 1024 + 4 * threadIdx.x;
    const float* y0 = ybuf + (size_t)(4 * o) * D + col;
    float4v v0 = *(const float4v*)(y0);
    float4v v1 = *(const float4v*)(y0 + D);
    float4v v2 = *(const float4v*)(y0 + 2 * D);
    float4v v3 = *(const float4v*)(y0 + 3 * D);
    float4v s;
    #pragma unroll
    for (int k = 0; k < 4; ++k) s[k] = (v0[k] + v1[k]) + (v2[k] + v3[k]);
    *(float4v*)(out + (size_t)o * D + col) = s;
}

extern "C" void kernel_launch(void* const* d_in, const int* in_sizes, int n_in,
                              void* d_out, int out_size, void* d_ws, size_t ws_size,
                              hipStream_t stream) {
    const float* x    = (const float*)d_in[0];
    const float* A    = (const float*)d_in[1];
    const float* B    = (const float*)d_in[2];
    const int*   xids = (const int*)d_in[3];
    const int*   wids = (const int*)d_in[4];
    float*       out  = (float*)d_out;

    float* ybuf = (float*)d_ws;   // [1024][4096] f32 = 16 MB

    hipLaunchKernelGGL(fused_kernel, dim3(NW), dim3(1024), 0, stream,
                       x, A, B, xids, wids, ybuf, out);
    hipLaunchKernelGGL(sum4_kernel, dim3(NBL * 4), dim3(256), 0, stream,
                       ybuf, out);
}